// Round 11
// baseline (133.031 us; speedup 1.0000x reference)
//
#include <hip/hip_runtime.h>

namespace {
constexpr int kL0 = 16384;
constexpr int kN1 = 8195;
constexpr int kN2 = 4101;

constexpr float RLc[8] = {
     0.23037781330885523f,  0.7148465705525415f,   0.6308807679295904f,
    -0.02798376941698385f, -0.18703481171888114f,  0.030841381835986965f,
     0.032883011666982945f, -0.010597401785069032f };

// Composite 3-level low-reconstruction bank (verified R5-R10):
// low[8q+r] = sum_m W[r][m]*a3[q+m]
struct WT { float w[8][7]; };
constexpr WT make_w() {
    WT W{};
    for (int r = 0; r < 8; ++r) {
        const int r2 = r >> 1, pi = r & 1;
        for (int u = 0; u < 4; ++u) {
            const float cu = RLc[6 + pi - 2 * u];
            const int k = r2 + u, k2 = k >> 1, pk = k & 1;
            for (int s = 0; s < 4; ++s) {
                const float cs = RLc[6 + pk - 2 * s];
                const int j = k2 + s, j2 = j >> 1, pj = j & 1;
                for (int t = 0; t < 4; ++t)
                    W.w[r][j2 + t] += cu * cs * RLc[6 + pj - 2 * t];
            }
        }
    }
    return W;
}

// Composite 3-level analysis low-pass, float4-aligned window (verified R8/R9):
// a3[n] = sum_{e=2..51} H3P[e] * x[8n-44+e]
struct H3PT { float v[52]; };
constexpr H3PT make_h3p() {
    H3PT h{};
    for (int a = 0; a < 8; ++a)
        for (int b = 0; b < 8; ++b)
            for (int c = 0; c < 8; ++c)
                h.v[2 + 4 * a + 2 * b + c] += RLc[a] * RLc[b] * RLc[c];
    return h;
}

__device__ constexpr float RL[8] = {
     0.23037781330885523f,  0.7148465705525415f,   0.6308807679295904f,
    -0.02798376941698385f, -0.18703481171888114f,  0.030841381835986965f,
     0.032883011666982945f, -0.010597401785069032f };
__device__ constexpr WT W = make_w();
__device__ constexpr H3PT H3P = make_h3p();
} // namespace

__device__ __forceinline__ int reflect(int g, int N) {
    if (g < 0)  g = -1 - g;
    if (g >= N) g = 2 * N - 1 - g;
    return g;
}

// direct a3 for interior n in [6, 2047]: reads x[8n-44 .. 8n+7]
__device__ __forceinline__ float a3_direct(const float* __restrict__ xr, int n) {
    const float4* __restrict__ p = reinterpret_cast<const float4*>(xr + (8 * n - 44));
    const float4 v0 = p[0];
    float s0 = v0.z * H3P.v[2];
    float s1 = v0.w * H3P.v[3];
    #pragma unroll
    for (int c = 1; c < 13; ++c) {
        const float4 v = p[c];
        s0 = fmaf(v.x, H3P.v[4 * c + 0], s0);
        s1 = fmaf(v.y, H3P.v[4 * c + 1], s1);
        s0 = fmaf(v.z, H3P.v[4 * c + 2], s0);
        s1 = fmaf(v.w, H3P.v[4 * c + 3], s1);
    }
    return s0 + s1;
}

// Wave-autonomous: wave (row, w) owns outputs [512w, 512w+511]. No LDS, no barriers.
__global__ void __launch_bounds__(256, 6)
wavelet_wavestream(const float* __restrict__ x, float* __restrict__ out, int rows) {
    const int tid  = threadIdx.x;
    const int lane = tid & 63;
    const int wv   = tid >> 6;
    const int b    = blockIdx.x;
    const int row  = b >> 3;                  // 8 blocks per row
    const int w    = ((b & 7) << 2) | wv;     // wave index 0..31 within row
    const float* __restrict__ xr = x + (size_t)row * kL0;

    // ---- boundary a3 recursion, all in-register (R8-verified index sets) ----
    // a3b[n], n in [0,5] u [2048,2053] ends up in lanes 0..11.
    float a3v = 0.f;
    if (w == 0 || w == 31) {
        const int i = (lane < 24) ? lane : 8174 + (lane - 24);   // lanes>=45: garbage, unused
        float a1v = 0.f;
        #pragma unroll
        for (int k = 0; k < 8; ++k)
            a1v = fmaf(xr[reflect(2 * i - 6 + k, kL0)], RL[k], a1v);
        const int j = (lane < 12) ? lane : 4090 + (lane - 12);   // lanes>=23: garbage
        float a2v = 0.f;
        #pragma unroll
        for (int k = 0; k < 8; ++k) {
            const int ii = reflect(2 * j - 6 + k, kN1);
            const int sl = (ii <= 23) ? ii : 24 + (ii - 8174);
            a2v = fmaf(__shfl(a1v, sl, 64), RL[k], a2v);
        }
        const int n = (lane < 6) ? lane : 2048 + (lane - 6);     // lanes>=12: garbage
        #pragma unroll
        for (int k = 0; k < 8; ++k) {
            const int jj = reflect(2 * n - 6 + k, kN2);
            const int sl = (jj <= 11) ? jj : 12 + (jj - 4090);
            a3v = fmaf(__shfl(a2v, sl, 64), RL[k], a3v);
        }
    }
    const float ownb  = __shfl(a3v, (lane < 6) ? lane : 0, 64);      // a3b[lane], w==0
    const float extrb = __shfl(a3v, 6 + ((lane < 6) ? lane : 0), 64);// a3b[6+lane], w==31

    // ---- own a3 + free x re-read from taps 11/12 ----
    const int n0 = (w << 6) | lane;           // 64w + lane, <= 2047
    float own;
    float4 x11, x12;
    if (w == 0 && lane < 6) {
        own = ownb;
        x11 = *reinterpret_cast<const float4*>(xr + 8 * n0);
        x12 = *reinterpret_cast<const float4*>(xr + 8 * n0 + 4);
    } else {
        const float4* __restrict__ p =
            reinterpret_cast<const float4*>(xr + (8 * n0 - 44));
        const float4 v0 = p[0];
        float s0 = v0.z * H3P.v[2];
        float s1 = v0.w * H3P.v[3];
        #pragma unroll
        for (int c = 1; c < 13; ++c) {
            const float4 v = p[c];
            if (c == 11) x11 = v;            // = x[8n0 .. 8n0+3]
            if (c == 12) x12 = v;            // = x[8n0+4 .. 8n0+7]
            s0 = fmaf(v.x, H3P.v[4 * c + 0], s0);
            s1 = fmaf(v.y, H3P.v[4 * c + 1], s1);
            s0 = fmaf(v.z, H3P.v[4 * c + 2], s0);
            s1 = fmaf(v.w, H3P.v[4 * c + 3], s1);
        }
        own = s0 + s1;
    }

    // ---- extra a3 (lanes 0..5 hold a3[64w+64+lane]) ----
    float extra = 0.f;
    if (lane < 6)
        extra = (w == 31) ? extrb : a3_direct(xr, ((w + 1) << 6) | lane);

    // ---- gather a[m] = a3[n0+m] via register shuffles ----
    float a[7];
    a[0] = own;
    #pragma unroll
    for (int m = 1; m < 7; ++m) {
        const int sl = (lane + m) & 63;
        const float va = __shfl(own,   sl, 64);
        const float vb = __shfl(extra, sl, 64);
        a[m] = (lane + m < 64) ? va : vb;
    }

    // ---- low = W * a3; high = x - low; proven interleaved float4 stores ----
    float lo[8];
    #pragma unroll
    for (int r = 0; r < 8; ++r) {
        float s = a[0] * W.w[r][0];
        #pragma unroll
        for (int m = 1; m < 7; ++m) s = fmaf(a[m], W.w[r][m], s);
        lo[r] = s;
    }
    float* __restrict__ lowp  = out + (size_t)row * kL0 + (w << 9) + (lane << 3);
    float* __restrict__ highp = lowp + (size_t)rows * kL0;
    reinterpret_cast<float4*>(lowp)[0]  = make_float4(lo[0], lo[1], lo[2], lo[3]);
    reinterpret_cast<float4*>(lowp)[1]  = make_float4(lo[4], lo[5], lo[6], lo[7]);
    reinterpret_cast<float4*>(highp)[0] = make_float4(x11.x - lo[0], x11.y - lo[1],
                                                      x11.z - lo[2], x11.w - lo[3]);
    reinterpret_cast<float4*>(highp)[1] = make_float4(x12.x - lo[4], x12.y - lo[5],
                                                      x12.z - lo[6], x12.w - lo[7]);
}

extern "C" void kernel_launch(void* const* d_in, const int* in_sizes, int n_in,
                              void* d_out, int out_size, void* d_ws, size_t ws_size,
                              hipStream_t stream) {
    (void)n_in; (void)d_ws; (void)ws_size; (void)out_size;
    const float* x = (const float*)d_in[0];
    float* out = (float*)d_out;
    const int rows = in_sizes[0] / kL0;           // 2048
    const int blocks = rows * 8;                  // 16384
    hipLaunchKernelGGL(wavelet_wavestream, dim3(blocks), dim3(256), 0, stream,
                       x, out, rows);
}

// Round 12
// 96.094 us; speedup vs baseline: 1.3844x; 1.3844x over previous
//
#include <hip/hip_runtime.h>

namespace {
constexpr int kL0 = 16384;
constexpr int kN1 = 8195;
constexpr int kN2 = 4101;
constexpr int kThreads = 256;

constexpr int SXF = 2144;   // sx[t] <-> x[XB+t], XB = O-44; valid t in [2,2140)
constexpr int SA1 = 1066;
constexpr int SA2 = 530;
constexpr int SA3 = 262;

constexpr float RLc[8] = {
     0.23037781330885523f,  0.7148465705525415f,   0.6308807679295904f,
    -0.02798376941698385f, -0.18703481171888114f,  0.030841381835986965f,
     0.032883011666982945f, -0.010597401785069032f };

// Composite 3-level low-reconstruction bank (verified R5-R11):
// low[8q+r] = sum_m W[r][m]*a3[q+m]
struct WT { float w[8][7]; };
constexpr WT make_w() {
    WT W{};
    for (int r = 0; r < 8; ++r) {
        const int r2 = r >> 1, pi = r & 1;
        for (int u = 0; u < 4; ++u) {
            const float cu = RLc[6 + pi - 2 * u];
            const int k = r2 + u, k2 = k >> 1, pk = k & 1;
            for (int s = 0; s < 4; ++s) {
                const float cs = RLc[6 + pk - 2 * s];
                const int j = k2 + s, j2 = j >> 1, pj = j & 1;
                for (int t = 0; t < 4; ++t)
                    W.w[r][j2 + t] += cu * cs * RLc[6 + pj - 2 * t];
            }
        }
    }
    return W;
}

__device__ constexpr float RL[8] = {
     0.23037781330885523f,  0.7148465705525415f,   0.6308807679295904f,
    -0.02798376941698385f, -0.18703481171888114f,  0.030841381835986965f,
     0.032883011666982945f, -0.010597401785069032f };
__device__ constexpr WT W = make_w();
} // namespace

__device__ __forceinline__ int reflect(int g, int N) {
    if (g < 0)  g = -1 - g;
    if (g >= N) g = 2 * N - 1 - g;
    return g;
}

// 8-tap correlation; p at EVEN float index (8B-aligned), float2 reads
__device__ __forceinline__ float tap8f2(const float* __restrict__ p) {
    const float2* q = reinterpret_cast<const float2*>(p);
    const float2 q0 = q[0], q1 = q[1], q2 = q[2], q3 = q[3];
    float s = q0.x * RL[0];
    s = fmaf(q0.y, RL[1], s); s = fmaf(q1.x, RL[2], s); s = fmaf(q1.y, RL[3], s);
    s = fmaf(q2.x, RL[4], s); s = fmaf(q2.y, RL[5], s); s = fmaf(q3.x, RL[6], s);
    s = fmaf(q3.y, RL[7], s);
    return s;
}

// barrier with LDS-visibility only (no vmcnt drain) — R10-verified pattern
__device__ __forceinline__ void bar_lgkm() {
    asm volatile("s_waitcnt lgkmcnt(0)" ::: "memory");
    __builtin_amdgcn_s_barrier();
    asm volatile("" ::: "memory");
}
// barrier draining DMA/global loads as well
__device__ __forceinline__ void bar_full() {
    asm volatile("s_waitcnt vmcnt(0) lgkmcnt(0)" ::: "memory");
    __builtin_amdgcn_s_barrier();
    asm volatile("" ::: "memory");
}

typedef __attribute__((address_space(1))) const void gvoid_t;
typedef __attribute__((address_space(3))) void lvoid_t;

__global__ void __launch_bounds__(kThreads, 8)
wavelet_v12(const float* __restrict__ x, float* __restrict__ out, int rows) {
    __shared__ __align__(16) float sx [SXF];
    __shared__ __align__(16) float sa1[SA1 + 2];
    __shared__ __align__(16) float sa2[SA2 + 2];
    __shared__ __align__(16) float sa3[SA3 + 2];

    const int tid  = threadIdx.x;
    const int row  = blockIdx.x >> 3;
    const int tile = blockIdx.x & 7;
    const int O    = tile << 11;
    const int XB   = O - 44;
    const int A0   = (O >> 1) - 18;
    const int B0   = (O >> 2) - 6;
    const float* __restrict__ xr = x + (size_t)row * kL0;
    const bool edge = (tile == 0) || (tile == 7);

    // ---- hoisted final-phase x re-read: issue first, consume last ----
    const float4* xr4 = reinterpret_cast<const float4*>(xr + O + 8 * tid);
    const float4 xv0 = xr4[0], xv1 = xr4[1];

    // ---- stage x -> sx (interior: R7-verified DMA; edge: R5-verified path) ----
    if (!edge) {
        if (tid < 2) sx[2 + tid] = xr[XB + 2 + tid];
        const int wv = tid >> 6, lane = tid & 63;
        for (int c = wv; c <= 8; c += 4) {
            const int fo = 4 + (c << 8) + (lane << 2);   // 16B-aligned float offset
            if (c < 8 || lane < 22)                      // cover t in [4, 2140)
                __builtin_amdgcn_global_load_lds((gvoid_t*)(xr + XB + fo),
                                                 (lvoid_t*)(&sx[fo]), 16, 0, 0);
        }
    } else {
        const int t0  = (tile == 0) ? 44 : 4;
        const int thi = (tile == 0) ? 2140 : 2092;
        const int Nv  = (thi - t0) >> 2;
        for (int v = tid; v < Nv; v += kThreads) {
            const float4 val = *reinterpret_cast<const float4*>(xr + XB + t0 + 4 * v);
            sx[t0 + 4 * v]     = val.x; sx[t0 + 4 * v + 1] = val.y;
            sx[t0 + 4 * v + 2] = val.z; sx[t0 + 4 * v + 3] = val.w;
        }
        for (int t = 2 + tid; t < 2140; t += kThreads)
            if (t < t0 || t >= thi)
                sx[t] = xr[reflect(XB + t, kL0)];
    }
    bar_full();   // DMA + staging loads drained (xv loads too — issued earliest)

    // ---- a1: sa1[m] = a1ext[A0+m]; window sx[2m+2 .. 2m+9] ----
    if (!edge) {
        #pragma unroll
        for (int it = 0; it < 4; ++it) {
            const int m = tid + (it << 8);
            sa1[m] = tap8f2(&sx[2 * m + 2]);
        }
        if (tid < SA1 - 1024) {
            const int m = 1024 + tid;
            sa1[m] = tap8f2(&sx[2 * m + 2]);
        }
    } else {
        for (int m = tid; m < SA1; m += kThreads) {
            const int g  = A0 + m;
            const int mh = (g >= 0 && g < kN1) ? m : (reflect(g, kN1) - A0);
            sa1[m] = tap8f2(&sx[2 * mh + 2]);
        }
    }
    bar_lgkm();

    // ---- a2: sa2[m] = a2ext[B0+m]; window sa1[2j .. 2j+7] ----
    if (!edge) {
        sa2[tid]       = tap8f2(&sa1[2 * tid]);
        sa2[tid + 256] = tap8f2(&sa1[2 * (tid + 256)]);
        if (tid < SA2 - 512) {
            const int m = 512 + tid;
            sa2[m] = tap8f2(&sa1[2 * m]);
        }
    } else {
        for (int m = tid; m < SA2; m += kThreads) {
            const int g = B0 + m;
            const int j = (g >= 0 && g < kN2) ? m : (reflect(g, kN2) - B0);
            sa2[m] = tap8f2(&sa1[2 * j]);
        }
    }
    bar_lgkm();

    // ---- a3: sa3[m] = a3[O/8 + m]; never reflected at this level ----
    sa3[tid] = tap8f2(&sa2[2 * tid]);
    if (tid < SA3 - 256) {
        const int m = 256 + tid;
        sa3[m] = tap8f2(&sa2[2 * m]);
    }
    bar_lgkm();

    // ---- final: low = W * a3; high = x - low (champion layout) ----
    {
        float a[7];
        #pragma unroll
        for (int m = 0; m < 7; ++m) a[m] = sa3[tid + m];
        float lo[8];
        #pragma unroll
        for (int r = 0; r < 8; ++r) {
            float s = a[0] * W.w[r][0];
            #pragma unroll
            for (int m = 1; m < 7; ++m) s = fmaf(a[m], W.w[r][m], s);
            lo[r] = s;
        }
        float* __restrict__ lowp  = out + (size_t)row * kL0 + O + 8 * tid;
        float* __restrict__ highp = lowp + (size_t)rows * kL0;
        reinterpret_cast<float4*>(lowp)[0]  = make_float4(lo[0], lo[1], lo[2], lo[3]);
        reinterpret_cast<float4*>(lowp)[1]  = make_float4(lo[4], lo[5], lo[6], lo[7]);
        reinterpret_cast<float4*>(highp)[0] = make_float4(xv0.x - lo[0], xv0.y - lo[1],
                                                          xv0.z - lo[2], xv0.w - lo[3]);
        reinterpret_cast<float4*>(highp)[1] = make_float4(xv1.x - lo[4], xv1.y - lo[5],
                                                          xv1.z - lo[6], xv1.w - lo[7]);
    }
}

extern "C" void kernel_launch(void* const* d_in, const int* in_sizes, int n_in,
                              void* d_out, int out_size, void* d_ws, size_t ws_size,
                              hipStream_t stream) {
    (void)n_in; (void)d_ws; (void)ws_size; (void)out_size;
    const float* x = (const float*)d_in[0];
    float* out = (float*)d_out;
    const int rows = in_sizes[0] / kL0;           // 2048
    const int blocks = rows * 8;                  // 16384
    hipLaunchKernelGGL(wavelet_v12, dim3(blocks), dim3(kThreads), 0, stream,
                       x, out, rows);
}

// Round 13
// 93.293 us; speedup vs baseline: 1.4259x; 1.0300x over previous
//
#include <hip/hip_runtime.h>

namespace {
constexpr int kL0 = 16384;
constexpr int kN1 = 8195;
constexpr int kN2 = 4101;
constexpr int kThreads = 128;            // 2 waves per block
constexpr int kTS = 1024;                // outputs per tile
constexpr int kTilesPerRow = kL0 / kTS;  // 16

// sx[t] <-> x[XB+t], XB = O-44; needed t in [2, 1116)
constexpr int SXF = 1120;
constexpr int SA1 = 554;   // a1ext [O/2-18 , O/2+536)
constexpr int SA2 = 274;   // a2ext [O/4-6  , O/4+268)
constexpr int SA3 = 134;   // a3    [O/8    , O/8+134)

constexpr float RLc[8] = {
     0.23037781330885523f,  0.7148465705525415f,   0.6308807679295904f,
    -0.02798376941698385f, -0.18703481171888114f,  0.030841381835986965f,
     0.032883011666982945f, -0.010597401785069032f };

// Composite 3-level low-reconstruction bank (verified R5-R12):
// low[8q+r] = sum_m W[r][m]*a3[q+m]
struct WT { float w[8][7]; };
constexpr WT make_w() {
    WT W{};
    for (int r = 0; r < 8; ++r) {
        const int r2 = r >> 1, pi = r & 1;
        for (int u = 0; u < 4; ++u) {
            const float cu = RLc[6 + pi - 2 * u];
            const int k = r2 + u, k2 = k >> 1, pk = k & 1;
            for (int s = 0; s < 4; ++s) {
                const float cs = RLc[6 + pk - 2 * s];
                const int j = k2 + s, j2 = j >> 1, pj = j & 1;
                for (int t = 0; t < 4; ++t)
                    W.w[r][j2 + t] += cu * cs * RLc[6 + pj - 2 * t];
            }
        }
    }
    return W;
}

__device__ constexpr float RL[8] = {
     0.23037781330885523f,  0.7148465705525415f,   0.6308807679295904f,
    -0.02798376941698385f, -0.18703481171888114f,  0.030841381835986965f,
     0.032883011666982945f, -0.010597401785069032f };
__device__ constexpr WT W = make_w();
} // namespace

__device__ __forceinline__ int reflect(int g, int N) {
    if (g < 0)  g = -1 - g;
    if (g >= N) g = 2 * N - 1 - g;
    return g;
}

// 8-tap correlation; p at EVEN float index (8B-aligned), float2 reads
__device__ __forceinline__ float tap8f2(const float* __restrict__ p) {
    const float2* q = reinterpret_cast<const float2*>(p);
    const float2 q0 = q[0], q1 = q[1], q2 = q[2], q3 = q[3];
    float s = q0.x * RL[0];
    s = fmaf(q0.y, RL[1], s); s = fmaf(q1.x, RL[2], s); s = fmaf(q1.y, RL[3], s);
    s = fmaf(q2.x, RL[4], s); s = fmaf(q2.y, RL[5], s); s = fmaf(q3.x, RL[6], s);
    s = fmaf(q3.y, RL[7], s);
    return s;
}

// barrier with LDS-visibility only (no vmcnt drain) — R10/R12-verified
__device__ __forceinline__ void bar_lgkm() {
    asm volatile("s_waitcnt lgkmcnt(0)" ::: "memory");
    __builtin_amdgcn_s_barrier();
    asm volatile("" ::: "memory");
}
__device__ __forceinline__ void bar_full() {
    asm volatile("s_waitcnt vmcnt(0) lgkmcnt(0)" ::: "memory");
    __builtin_amdgcn_s_barrier();
    asm volatile("" ::: "memory");
}

typedef __attribute__((address_space(1))) const void gvoid_t;
typedef __attribute__((address_space(3))) void lvoid_t;

__global__ void __launch_bounds__(kThreads, 8)
wavelet_v13(const float* __restrict__ x, float* __restrict__ out, int rows) {
    __shared__ __align__(16) float sx [SXF];
    __shared__ __align__(16) float sa1[SA1 + 2];
    __shared__ __align__(16) float sa2[SA2 + 2];
    __shared__ __align__(16) float sa3[SA3 + 2];

    const int tid  = threadIdx.x;
    const int row  = blockIdx.x >> 4;         // 16 tiles per row
    const int tile = blockIdx.x & 15;
    const int O    = tile << 10;
    const int XB   = O - 44;
    const int A0   = (O >> 1) - 18;
    const int B0   = (O >> 2) - 6;
    const float* __restrict__ xr = x + (size_t)row * kL0;
    const bool edge = (tile == 0) || (tile == kTilesPerRow - 1);

    // ---- hoisted final-phase x re-read: issue first, consume last ----
    const float4* xr4 = reinterpret_cast<const float4*>(xr + O + 8 * tid);
    const float4 xv0 = xr4[0], xv1 = xr4[1];

    // ---- stage x -> sx ----
    if (!edge) {
        if (tid < 2) sx[2 + tid] = xr[XB + 2 + tid];
        const int wv = tid >> 6, lane = tid & 63;
        for (int c = wv; c <= 4; c += 2) {
            const int fo = 4 + (c << 8) + (lane << 2);   // 16B-aligned float offset
            if (c < 4 || lane < 22)                      // cover t in [4, 1116)
                __builtin_amdgcn_global_load_lds((gvoid_t*)(xr + XB + fo),
                                                 (lvoid_t*)(&sx[fo]), 16, 0, 0);
        }
    } else {
        const int t0  = (tile == 0) ? 44 : 4;
        const int thi = (tile == 0) ? 1116 : 1068;   // tile 15: x ends at t=1067
        const int Nv  = (thi - t0) >> 2;
        for (int v = tid; v < Nv; v += kThreads) {
            const float4 val = *reinterpret_cast<const float4*>(xr + XB + t0 + 4 * v);
            sx[t0 + 4 * v]     = val.x; sx[t0 + 4 * v + 1] = val.y;
            sx[t0 + 4 * v + 2] = val.z; sx[t0 + 4 * v + 3] = val.w;
        }
        for (int t = 2 + tid; t < 1116; t += kThreads)
            if (t < t0 || t >= thi)
                sx[t] = xr[reflect(XB + t, kL0)];
    }
    bar_full();

    // ---- a1: sa1[m] = a1ext[A0+m]; window sx[2m+2 .. 2m+9] ----
    if (!edge) {
        #pragma unroll
        for (int it = 0; it < 4; ++it) {
            const int m = tid + (it << 7);
            sa1[m] = tap8f2(&sx[2 * m + 2]);
        }
        if (tid < SA1 - 512) {
            const int m = 512 + tid;
            sa1[m] = tap8f2(&sx[2 * m + 2]);
        }
    } else {
        for (int m = tid; m < SA1; m += kThreads) {
            const int g  = A0 + m;
            const int mh = (g >= 0 && g < kN1) ? m : (reflect(g, kN1) - A0);
            sa1[m] = tap8f2(&sx[2 * mh + 2]);
        }
    }
    bar_lgkm();

    // ---- a2: sa2[m] = a2ext[B0+m]; window sa1[2j .. 2j+7] ----
    if (!edge) {
        sa2[tid]       = tap8f2(&sa1[2 * tid]);
        sa2[tid + 128] = tap8f2(&sa1[2 * (tid + 128)]);
        if (tid < SA2 - 256) {
            const int m = 256 + tid;
            sa2[m] = tap8f2(&sa1[2 * m]);
        }
    } else {
        for (int m = tid; m < SA2; m += kThreads) {
            const int g = B0 + m;
            const int j = (g >= 0 && g < kN2) ? m : (reflect(g, kN2) - B0);
            sa2[m] = tap8f2(&sa1[2 * j]);
        }
    }
    bar_lgkm();

    // ---- a3: sa3[m] = a3[O/8 + m]; never reflected at this level ----
    sa3[tid] = tap8f2(&sa2[2 * tid]);
    if (tid < SA3 - 128) {
        const int m = 128 + tid;
        sa3[m] = tap8f2(&sa2[2 * m]);
    }
    bar_lgkm();

    // ---- final: low = W * a3; high = x - low (champion layout) ----
    {
        float a[7];
        #pragma unroll
        for (int m = 0; m < 7; ++m) a[m] = sa3[tid + m];
        float lo[8];
        #pragma unroll
        for (int r = 0; r < 8; ++r) {
            float s = a[0] * W.w[r][0];
            #pragma unroll
            for (int m = 1; m < 7; ++m) s = fmaf(a[m], W.w[r][m], s);
            lo[r] = s;
        }
        float* __restrict__ lowp  = out + (size_t)row * kL0 + O + 8 * tid;
        float* __restrict__ highp = lowp + (size_t)rows * kL0;
        reinterpret_cast<float4*>(lowp)[0]  = make_float4(lo[0], lo[1], lo[2], lo[3]);
        reinterpret_cast<float4*>(lowp)[1]  = make_float4(lo[4], lo[5], lo[6], lo[7]);
        reinterpret_cast<float4*>(highp)[0] = make_float4(xv0.x - lo[0], xv0.y - lo[1],
                                                          xv0.z - lo[2], xv0.w - lo[3]);
        reinterpret_cast<float4*>(highp)[1] = make_float4(xv1.x - lo[4], xv1.y - lo[5],
                                                          xv1.z - lo[6], xv1.w - lo[7]);
    }
}

extern "C" void kernel_launch(void* const* d_in, const int* in_sizes, int n_in,
                              void* d_out, int out_size, void* d_ws, size_t ws_size,
                              hipStream_t stream) {
    (void)n_in; (void)d_ws; (void)ws_size; (void)out_size;
    const float* x = (const float*)d_in[0];
    float* out = (float*)d_out;
    const int rows = in_sizes[0] / kL0;                 // 2048
    const int blocks = rows * kTilesPerRow;             // 32768
    hipLaunchKernelGGL(wavelet_v13, dim3(blocks), dim3(kThreads), 0, stream,
                       x, out, rows);
}

// Round 14
// 89.887 us; speedup vs baseline: 1.4800x; 1.0379x over previous
//
#include <hip/hip_runtime.h>

namespace {
constexpr int kL0 = 16384;
constexpr int kN1 = 8195;
constexpr int kN2 = 4101;
constexpr int kThreads = 128;            // 2 waves per block
constexpr int kTS = 1024;                // outputs per tile
constexpr int kTilesPerRow = kL0 / kTS;  // 16

// edge-path staging: sx[t] <-> x[XB+t], XB = O-44; needed t in [2, 1116)
constexpr int SXF = 1120;
constexpr int SA1 = 554;   // a1ext [O/2-18 , O/2+536)
constexpr int SA2 = 274;   // a2ext [O/4-6  , O/4+268)
constexpr int SA3 = 134;   // a3    [O/8    , O/8+134)

constexpr float RLc[8] = {
     0.23037781330885523f,  0.7148465705525415f,   0.6308807679295904f,
    -0.02798376941698385f, -0.18703481171888114f,  0.030841381835986965f,
     0.032883011666982945f, -0.010597401785069032f };

// Composite 3-level low-reconstruction bank (verified R5-R13):
// low[8q+r] = sum_m W[r][m]*a3[q+m]
struct WT { float w[8][7]; };
constexpr WT make_w() {
    WT W{};
    for (int r = 0; r < 8; ++r) {
        const int r2 = r >> 1, pi = r & 1;
        for (int u = 0; u < 4; ++u) {
            const float cu = RLc[6 + pi - 2 * u];
            const int k = r2 + u, k2 = k >> 1, pk = k & 1;
            for (int s = 0; s < 4; ++s) {
                const float cs = RLc[6 + pk - 2 * s];
                const int j = k2 + s, j2 = j >> 1, pj = j & 1;
                for (int t = 0; t < 4; ++t)
                    W.w[r][j2 + t] += cu * cs * RLc[6 + pj - 2 * t];
            }
        }
    }
    return W;
}

__device__ constexpr float RL[8] = {
     0.23037781330885523f,  0.7148465705525415f,   0.6308807679295904f,
    -0.02798376941698385f, -0.18703481171888114f,  0.030841381835986965f,
     0.032883011666982945f, -0.010597401785069032f };
__device__ constexpr WT W = make_w();
} // namespace

__device__ __forceinline__ int reflect(int g, int N) {
    if (g < 0)  g = -1 - g;
    if (g >= N) g = 2 * N - 1 - g;
    return g;
}

// 8-tap correlation; p at EVEN float index (8B-aligned), float2 reads
__device__ __forceinline__ float tap8f2(const float* __restrict__ p) {
    const float2* q = reinterpret_cast<const float2*>(p);
    const float2 q0 = q[0], q1 = q[1], q2 = q[2], q3 = q[3];
    float s = q0.x * RL[0];
    s = fmaf(q0.y, RL[1], s); s = fmaf(q1.x, RL[2], s); s = fmaf(q1.y, RL[3], s);
    s = fmaf(q2.x, RL[4], s); s = fmaf(q2.y, RL[5], s); s = fmaf(q3.x, RL[6], s);
    s = fmaf(q3.y, RL[7], s);
    return s;
}

// barrier with LDS-visibility only (no vmcnt drain) — R10/R12/R13-verified
__device__ __forceinline__ void bar_lgkm() {
    asm volatile("s_waitcnt lgkmcnt(0)" ::: "memory");
    __builtin_amdgcn_s_barrier();
    asm volatile("" ::: "memory");
}
__device__ __forceinline__ void bar_full() {
    asm volatile("s_waitcnt vmcnt(0) lgkmcnt(0)" ::: "memory");
    __builtin_amdgcn_s_barrier();
    asm volatile("" ::: "memory");
}

__global__ void __launch_bounds__(kThreads, 8)
wavelet_v14(const float* __restrict__ x, float* __restrict__ out, int rows) {
    __shared__ __align__(16) float sx [SXF];          // edge path only
    __shared__ __align__(16) float sa1[SA1 + 2];
    __shared__ __align__(16) float sa2[SA2 + 2];
    __shared__ __align__(16) float sa3[SA3 + 2];

    const int tid  = threadIdx.x;
    const int row  = blockIdx.x >> 4;         // 16 tiles per row
    const int tile = blockIdx.x & 15;
    const int O    = tile << 10;
    const int XB   = O - 44;
    const int A0   = (O >> 1) - 18;
    const int B0   = (O >> 2) - 6;
    const float* __restrict__ xr = x + (size_t)row * kL0;
    const bool edge = (tile == 0) || (tile == kTilesPerRow - 1);

    // ---- hoisted final-phase x re-read: issue first, consume last ----
    const float4* xr4 = reinterpret_cast<const float4*>(xr + O + 8 * tid);
    const float4 xv0 = xr4[0], xv1 = xr4[1];

    if (!edge) {
        // ==== interior: level-1 in registers, no sx staging, no vm drain ====
        // pass 0: m0 = 4*tid (0..508); pass 1: m0 = 512+4*tid (tid<=10)
        #pragma unroll
        for (int pass = 0; pass < 2; ++pass) {
            const int m0 = 4 * tid + (pass << 9);
            if (m0 < SA1) {
                // 16 floats e[0..15] = x[O-44+2*m0 .. +15]; 16B-aligned base
                const float4* __restrict__ p =
                    reinterpret_cast<const float4*>(xr + (O - 44 + 2 * m0));
                const float4 u = p[0], v = p[1], w2 = p[2], z = p[3];
                const float e[16] = {u.x, u.y, u.z, u.w, v.x, v.y, v.z, v.w,
                                     w2.x, w2.y, w2.z, w2.w, z.x, z.y, z.z, z.w};
                float o[4];
                #pragma unroll
                for (int i = 0; i < 4; ++i) {
                    // a1[A0+m0+i] window = e[2+2i .. 9+2i]
                    float s = e[2 + 2 * i] * RL[0];
                    #pragma unroll
                    for (int k = 1; k < 8; ++k)
                        s = fmaf(e[2 + 2 * i + k], RL[k], s);
                    o[i] = s;
                }
                if (m0 + 3 < SA1) {
                    *reinterpret_cast<float4*>(&sa1[m0]) =
                        make_float4(o[0], o[1], o[2], o[3]);
                } else {
                    #pragma unroll
                    for (int i = 0; i < 4; ++i)
                        if (m0 + i < SA1) sa1[m0 + i] = o[i];
                }
            }
        }
        bar_lgkm();

        // ---- a2: sa2[m] = a2[B0+m]; window sa1[2m .. 2m+7] ----
        sa2[tid]       = tap8f2(&sa1[2 * tid]);
        sa2[tid + 128] = tap8f2(&sa1[2 * (tid + 128)]);
        if (tid < SA2 - 256) {
            const int m = 256 + tid;
            sa2[m] = tap8f2(&sa1[2 * m]);
        }
        bar_lgkm();

        // ---- a3 ----
        sa3[tid] = tap8f2(&sa2[2 * tid]);
        if (tid < SA3 - 128) {
            const int m = 128 + tid;
            sa3[m] = tap8f2(&sa2[2 * m]);
        }
        bar_lgkm();
    } else {
        // ==== edge: R13-verified staged pyramid with per-level reflection ====
        const int t0  = (tile == 0) ? 44 : 4;
        const int thi = (tile == 0) ? 1116 : 1068;
        const int Nv  = (thi - t0) >> 2;
        for (int v = tid; v < Nv; v += kThreads) {
            const float4 val = *reinterpret_cast<const float4*>(xr + XB + t0 + 4 * v);
            sx[t0 + 4 * v]     = val.x; sx[t0 + 4 * v + 1] = val.y;
            sx[t0 + 4 * v + 2] = val.z; sx[t0 + 4 * v + 3] = val.w;
        }
        for (int t = 2 + tid; t < 1116; t += kThreads)
            if (t < t0 || t >= thi)
                sx[t] = xr[reflect(XB + t, kL0)];
        bar_full();

        for (int m = tid; m < SA1; m += kThreads) {
            const int g  = A0 + m;
            const int mh = (g >= 0 && g < kN1) ? m : (reflect(g, kN1) - A0);
            sa1[m] = tap8f2(&sx[2 * mh + 2]);
        }
        bar_lgkm();

        for (int m = tid; m < SA2; m += kThreads) {
            const int g = B0 + m;
            const int j = (g >= 0 && g < kN2) ? m : (reflect(g, kN2) - B0);
            sa2[m] = tap8f2(&sa1[2 * j]);
        }
        bar_lgkm();

        for (int m = tid; m < SA3; m += kThreads)
            sa3[m] = tap8f2(&sa2[2 * m]);
        bar_lgkm();
    }

    // ---- final: low = W * a3; high = x - low (champion layout) ----
    {
        float a[7];
        #pragma unroll
        for (int m = 0; m < 7; ++m) a[m] = sa3[tid + m];
        float lo[8];
        #pragma unroll
        for (int r = 0; r < 8; ++r) {
            float s = a[0] * W.w[r][0];
            #pragma unroll
            for (int m = 1; m < 7; ++m) s = fmaf(a[m], W.w[r][m], s);
            lo[r] = s;
        }
        float* __restrict__ lowp  = out + (size_t)row * kL0 + O + 8 * tid;
        float* __restrict__ highp = lowp + (size_t)rows * kL0;
        reinterpret_cast<float4*>(lowp)[0]  = make_float4(lo[0], lo[1], lo[2], lo[3]);
        reinterpret_cast<float4*>(lowp)[1]  = make_float4(lo[4], lo[5], lo[6], lo[7]);
        reinterpret_cast<float4*>(highp)[0] = make_float4(xv0.x - lo[0], xv0.y - lo[1],
                                                          xv0.z - lo[2], xv0.w - lo[3]);
        reinterpret_cast<float4*>(highp)[1] = make_float4(xv1.x - lo[4], xv1.y - lo[5],
                                                          xv1.z - lo[6], xv1.w - lo[7]);
    }
}

extern "C" void kernel_launch(void* const* d_in, const int* in_sizes, int n_in,
                              void* d_out, int out_size, void* d_ws, size_t ws_size,
                              hipStream_t stream) {
    (void)n_in; (void)d_ws; (void)ws_size; (void)out_size;
    const float* x = (const float*)d_in[0];
    float* out = (float*)d_out;
    const int rows = in_sizes[0] / kL0;                 // 2048
    const int blocks = rows * kTilesPerRow;             // 32768
    hipLaunchKernelGGL(wavelet_v14, dim3(blocks), dim3(kThreads), 0, stream,
                       x, out, rows);
}

// Round 15
// 82.303 us; speedup vs baseline: 1.6164x; 1.0921x over previous
//
#include <hip/hip_runtime.h>

namespace {
constexpr int kL0 = 16384;
constexpr int kN1 = 8195;
constexpr int kN2 = 4101;
constexpr int kThreads = 128;            // 2 waves per block
constexpr int kTS = 1024;                // outputs per tile
constexpr int kTilesPerRow = kL0 / kTS;  // 16

// edge-path staging: sx[t] <-> x[XB+t], XB = O-44; needed t in [2, 1116)
constexpr int SXF = 1120;
constexpr int SA1 = 554;   // a1ext [O/2-18 , O/2+536)
constexpr int SA2 = 274;   // a2ext [O/4-6  , O/4+268)
constexpr int SA3 = 134;   // a3    [O/8    , O/8+134)

constexpr float RLc[8] = {
     0.23037781330885523f,  0.7148465705525415f,   0.6308807679295904f,
    -0.02798376941698385f, -0.18703481171888114f,  0.030841381835986965f,
     0.032883011666982945f, -0.010597401785069032f };

// Composite 3-level low-reconstruction bank (verified R5-R14):
// low[8q+r] = sum_m W[r][m]*a3[q+m]
struct WT { float w[8][7]; };
constexpr WT make_w() {
    WT W{};
    for (int r = 0; r < 8; ++r) {
        const int r2 = r >> 1, pi = r & 1;
        for (int u = 0; u < 4; ++u) {
            const float cu = RLc[6 + pi - 2 * u];
            const int k = r2 + u, k2 = k >> 1, pk = k & 1;
            for (int s = 0; s < 4; ++s) {
                const float cs = RLc[6 + pk - 2 * s];
                const int j = k2 + s, j2 = j >> 1, pj = j & 1;
                for (int t = 0; t < 4; ++t)
                    W.w[r][j2 + t] += cu * cs * RLc[6 + pj - 2 * t];
            }
        }
    }
    return W;
}

__device__ constexpr float RL[8] = {
     0.23037781330885523f,  0.7148465705525415f,   0.6308807679295904f,
    -0.02798376941698385f, -0.18703481171888114f,  0.030841381835986965f,
     0.032883011666982945f, -0.010597401785069032f };
__device__ constexpr WT W = make_w();

typedef float vfloat4 __attribute__((ext_vector_type(4)));
} // namespace

__device__ __forceinline__ int reflect(int g, int N) {
    if (g < 0)  g = -1 - g;
    if (g >= N) g = 2 * N - 1 - g;
    return g;
}

// 8-tap correlation; p at EVEN float index (8B-aligned), float2 reads
__device__ __forceinline__ float tap8f2(const float* __restrict__ p) {
    const float2* q = reinterpret_cast<const float2*>(p);
    const float2 q0 = q[0], q1 = q[1], q2 = q[2], q3 = q[3];
    float s = q0.x * RL[0];
    s = fmaf(q0.y, RL[1], s); s = fmaf(q1.x, RL[2], s); s = fmaf(q1.y, RL[3], s);
    s = fmaf(q2.x, RL[4], s); s = fmaf(q2.y, RL[5], s); s = fmaf(q3.x, RL[6], s);
    s = fmaf(q3.y, RL[7], s);
    return s;
}

// barrier with LDS-visibility only (no vmcnt drain) — R10/R12-R14-verified
__device__ __forceinline__ void bar_lgkm() {
    asm volatile("s_waitcnt lgkmcnt(0)" ::: "memory");
    __builtin_amdgcn_s_barrier();
    asm volatile("" ::: "memory");
}
__device__ __forceinline__ void bar_full() {
    asm volatile("s_waitcnt vmcnt(0) lgkmcnt(0)" ::: "memory");
    __builtin_amdgcn_s_barrier();
    asm volatile("" ::: "memory");
}

__global__ void __launch_bounds__(kThreads, 8)
wavelet_v15(const float* __restrict__ x, float* __restrict__ out, int rows) {
    __shared__ __align__(16) float sx [SXF];          // edge path only
    __shared__ __align__(16) float sa1[SA1 + 2];      // edge path only
    __shared__ __align__(16) float sa2[SA2 + 2];
    __shared__ __align__(16) float sa3[SA3 + 2];

    const int tid  = threadIdx.x;
    const int row  = blockIdx.x >> 4;         // 16 tiles per row
    const int tile = blockIdx.x & 15;
    const int O    = tile << 10;
    const int XB   = O - 44;
    const int A0   = (O >> 1) - 18;
    const int B0   = (O >> 2) - 6;
    const float* __restrict__ xr = x + (size_t)row * kL0;
    const bool edge = (tile == 0) || (tile == kTilesPerRow - 1);

    // ---- hoisted final-phase x re-read: issue first, consume last ----
    const float4* xr4 = reinterpret_cast<const float4*>(xr + O + 8 * tid);
    const float4 xv0 = xr4[0], xv1 = xr4[1];

    if (!edge) {
        // ==== interior: levels 1+2 in registers; sa2 is the first LDS write ====
        // pass 0: m0 = 2*tid (0..254); pass 1: m0 = 256+2*tid (tid<9)
        #pragma unroll
        for (int pass = 0; pass < 2; ++pass) {
            const int m0 = (pass == 0) ? (2 * tid) : (256 + 2 * tid);
            if (pass == 0 || tid < 9) {
                // e[d] = x[XB + 4*m0 + d], d in [0,28); base 16B-aligned
                const float4* __restrict__ p =
                    reinterpret_cast<const float4*>(xr + XB + 4 * m0);
                float e[28];
                #pragma unroll
                for (int c = 0; c < 7; ++c) {
                    const float4 v = p[c];
                    e[4 * c] = v.x; e[4 * c + 1] = v.y;
                    e[4 * c + 2] = v.z; e[4 * c + 3] = v.w;
                }
                // a1 local j = 2*m0+u, u=0..9: window e[2u+2 .. 2u+9]
                float a1r[10];
                #pragma unroll
                for (int u = 0; u < 10; ++u) {
                    float s = e[2 * u + 2] * RL[0];
                    #pragma unroll
                    for (int k = 1; k < 8; ++k)
                        s = fmaf(e[2 * u + 2 + k], RL[k], s);
                    a1r[u] = s;
                }
                // a2[m0+i], i=0,1: window a1r[2i .. 2i+7]
                float o[2];
                #pragma unroll
                for (int i = 0; i < 2; ++i) {
                    float s = a1r[2 * i] * RL[0];
                    #pragma unroll
                    for (int k = 1; k < 8; ++k)
                        s = fmaf(a1r[2 * i + k], RL[k], s);
                    o[i] = s;
                }
                *reinterpret_cast<float2*>(&sa2[m0]) = make_float2(o[0], o[1]);
            }
        }
        bar_lgkm();

        // ---- a3 ----
        sa3[tid] = tap8f2(&sa2[2 * tid]);
        if (tid < SA3 - 128) {
            const int m = 128 + tid;
            sa3[m] = tap8f2(&sa2[2 * m]);
        }
        bar_lgkm();
    } else {
        // ==== edge: R13-verified staged pyramid with per-level reflection ====
        const int t0  = (tile == 0) ? 44 : 4;
        const int thi = (tile == 0) ? 1116 : 1068;
        const int Nv  = (thi - t0) >> 2;
        for (int v = tid; v < Nv; v += kThreads) {
            const float4 val = *reinterpret_cast<const float4*>(xr + XB + t0 + 4 * v);
            sx[t0 + 4 * v]     = val.x; sx[t0 + 4 * v + 1] = val.y;
            sx[t0 + 4 * v + 2] = val.z; sx[t0 + 4 * v + 3] = val.w;
        }
        for (int t = 2 + tid; t < 1116; t += kThreads)
            if (t < t0 || t >= thi)
                sx[t] = xr[reflect(XB + t, kL0)];
        bar_full();

        for (int m = tid; m < SA1; m += kThreads) {
            const int g  = A0 + m;
            const int mh = (g >= 0 && g < kN1) ? m : (reflect(g, kN1) - A0);
            sa1[m] = tap8f2(&sx[2 * mh + 2]);
        }
        bar_lgkm();

        for (int m = tid; m < SA2; m += kThreads) {
            const int g = B0 + m;
            const int j = (g >= 0 && g < kN2) ? m : (reflect(g, kN2) - B0);
            sa2[m] = tap8f2(&sa1[2 * j]);
        }
        bar_lgkm();

        for (int m = tid; m < SA3; m += kThreads)
            sa3[m] = tap8f2(&sa2[2 * m]);
        bar_lgkm();
    }

    // ---- final: low = W * a3; high = x - low; non-temporal stores ----
    {
        float a[7];
        #pragma unroll
        for (int m = 0; m < 7; ++m) a[m] = sa3[tid + m];
        float lo[8];
        #pragma unroll
        for (int r = 0; r < 8; ++r) {
            float s = a[0] * W.w[r][0];
            #pragma unroll
            for (int m = 1; m < 7; ++m) s = fmaf(a[m], W.w[r][m], s);
            lo[r] = s;
        }
        float* __restrict__ lowp  = out + (size_t)row * kL0 + O + 8 * tid;
        float* __restrict__ highp = lowp + (size_t)rows * kL0;
        vfloat4 l0 = {lo[0], lo[1], lo[2], lo[3]};
        vfloat4 l1 = {lo[4], lo[5], lo[6], lo[7]};
        vfloat4 h0 = {xv0.x - lo[0], xv0.y - lo[1], xv0.z - lo[2], xv0.w - lo[3]};
        vfloat4 h1 = {xv1.x - lo[4], xv1.y - lo[5], xv1.z - lo[6], xv1.w - lo[7]};
        __builtin_nontemporal_store(l0, reinterpret_cast<vfloat4*>(lowp));
        __builtin_nontemporal_store(l1, reinterpret_cast<vfloat4*>(lowp) + 1);
        __builtin_nontemporal_store(h0, reinterpret_cast<vfloat4*>(highp));
        __builtin_nontemporal_store(h1, reinterpret_cast<vfloat4*>(highp) + 1);
    }
}

extern "C" void kernel_launch(void* const* d_in, const int* in_sizes, int n_in,
                              void* d_out, int out_size, void* d_ws, size_t ws_size,
                              hipStream_t stream) {
    (void)n_in; (void)d_ws; (void)ws_size; (void)out_size;
    const float* x = (const float*)d_in[0];
    float* out = (float*)d_out;
    const int rows = in_sizes[0] / kL0;                 // 2048
    const int blocks = rows * kTilesPerRow;             // 32768
    hipLaunchKernelGGL(wavelet_v15, dim3(blocks), dim3(kThreads), 0, stream,
                       x, out, rows);
}

// Round 16
// 81.796 us; speedup vs baseline: 1.6264x; 1.0062x over previous
//
#include <hip/hip_runtime.h>

namespace {
constexpr int kL0 = 16384;
constexpr int kN1 = 8195;
constexpr int kN2 = 4101;
constexpr int kThreads = 128;            // 2 waves per block
constexpr int kTS = 1024;                // outputs per tile
constexpr int kTilesPerRow = kL0 / kTS;  // 16

// edge-path staging: sx[t] <-> x[XB+t], XB = O-44; needed t in [2, 1116)
constexpr int SXF = 1120;
constexpr int SA1 = 554;   // a1ext [O/2-18 , O/2+536)
constexpr int SA2 = 274;   // a2ext [O/4-6  , O/4+268)

constexpr float RLc[8] = {
     0.23037781330885523f,  0.7148465705525415f,   0.6308807679295904f,
    -0.02798376941698385f, -0.18703481171888114f,  0.030841381835986965f,
     0.032883011666982945f, -0.010597401785069032f };

// 3-level low-reconstruction bank (verified R5-R15): low[8q+r] = sum_m W[r][m]*a3[q+m]
struct WT { float w[8][7]; };
constexpr WT make_w() {
    WT W{};
    for (int r = 0; r < 8; ++r) {
        const int r2 = r >> 1, pi = r & 1;
        for (int u = 0; u < 4; ++u) {
            const float cu = RLc[6 + pi - 2 * u];
            const int k = r2 + u, k2 = k >> 1, pk = k & 1;
            for (int s = 0; s < 4; ++s) {
                const float cs = RLc[6 + pk - 2 * s];
                const int j = k2 + s, j2 = j >> 1, pj = j & 1;
                for (int t = 0; t < 4; ++t)
                    W.w[r][j2 + t] += cu * cs * RLc[6 + pj - 2 * t];
            }
        }
    }
    return W;
}

// W2 folds the a3 tap (a3 local m' = sum_k RL[k]*sa2[2m'+k], never reflected):
// low[8*tid+r] = sum_{j=0..19} W2[r][j] * sa2[2*tid+j]
struct W2T { float w[8][20]; };
constexpr W2T make_w2() {
    W2T W2{};
    const WT Wt = make_w();
    for (int r = 0; r < 8; ++r)
        for (int m = 0; m < 7; ++m)
            for (int k = 0; k < 8; ++k)
                W2.w[r][2 * m + k] += Wt.w[r][m] * RLc[k];
    return W2;
}

__device__ constexpr float RL[8] = {
     0.23037781330885523f,  0.7148465705525415f,   0.6308807679295904f,
    -0.02798376941698385f, -0.18703481171888114f,  0.030841381835986965f,
     0.032883011666982945f, -0.010597401785069032f };
__device__ constexpr W2T W2 = make_w2();

typedef float vfloat4 __attribute__((ext_vector_type(4)));
} // namespace

__device__ __forceinline__ int reflect(int g, int N) {
    if (g < 0)  g = -1 - g;
    if (g >= N) g = 2 * N - 1 - g;
    return g;
}

// 8-tap correlation; p at EVEN float index (8B-aligned), float2 reads
__device__ __forceinline__ float tap8f2(const float* __restrict__ p) {
    const float2* q = reinterpret_cast<const float2*>(p);
    const float2 q0 = q[0], q1 = q[1], q2 = q[2], q3 = q[3];
    float s = q0.x * RL[0];
    s = fmaf(q0.y, RL[1], s); s = fmaf(q1.x, RL[2], s); s = fmaf(q1.y, RL[3], s);
    s = fmaf(q2.x, RL[4], s); s = fmaf(q2.y, RL[5], s); s = fmaf(q3.x, RL[6], s);
    s = fmaf(q3.y, RL[7], s);
    return s;
}

// barrier with LDS-visibility only (no vmcnt drain) — R10/R12-R15-verified
__device__ __forceinline__ void bar_lgkm() {
    asm volatile("s_waitcnt lgkmcnt(0)" ::: "memory");
    __builtin_amdgcn_s_barrier();
    asm volatile("" ::: "memory");
}
__device__ __forceinline__ void bar_full() {
    asm volatile("s_waitcnt vmcnt(0) lgkmcnt(0)" ::: "memory");
    __builtin_amdgcn_s_barrier();
    asm volatile("" ::: "memory");
}

__global__ void __launch_bounds__(kThreads, 8)
wavelet_v16(const float* __restrict__ x, float* __restrict__ out, int rows) {
    __shared__ __align__(16) float sx [SXF];          // edge path only
    __shared__ __align__(16) float sa1[SA1 + 2];      // edge path only
    __shared__ __align__(16) float sa2[SA2 + 2];

    const int tid  = threadIdx.x;
    const int row  = blockIdx.x >> 4;         // 16 tiles per row
    const int tile = blockIdx.x & 15;
    const int O    = tile << 10;
    const int XB   = O - 44;
    const int A0   = (O >> 1) - 18;
    const int B0   = (O >> 2) - 6;
    const float* __restrict__ xr = x + (size_t)row * kL0;
    const bool edge = (tile == 0) || (tile == kTilesPerRow - 1);

    // ---- hoisted final-phase x re-read: issue first, consume last ----
    const float4* xr4 = reinterpret_cast<const float4*>(xr + O + 8 * tid);
    const float4 xv0 = xr4[0], xv1 = xr4[1];

    if (!edge) {
        // ==== interior: levels 1+2 in registers; sa2 is the only LDS write ====
        // pass 0: m0 = 2*tid (0..254); pass 1: m0 = 256+2*tid (tid<9)
        #pragma unroll
        for (int pass = 0; pass < 2; ++pass) {
            const int m0 = (pass == 0) ? (2 * tid) : (256 + 2 * tid);
            if (pass == 0 || tid < 9) {
                // e[d] = x[XB + 4*m0 + d], d in [0,28); base 16B-aligned
                const float4* __restrict__ p =
                    reinterpret_cast<const float4*>(xr + XB + 4 * m0);
                float e[28];
                #pragma unroll
                for (int c = 0; c < 7; ++c) {
                    const float4 v = p[c];
                    e[4 * c] = v.x; e[4 * c + 1] = v.y;
                    e[4 * c + 2] = v.z; e[4 * c + 3] = v.w;
                }
                // a1 local u = 0..9: a1[A0+2m0+u], window e[2u+2 .. 2u+9]
                float a1r[10];
                #pragma unroll
                for (int u = 0; u < 10; ++u) {
                    float s = e[2 * u + 2] * RL[0];
                    #pragma unroll
                    for (int k = 1; k < 8; ++k)
                        s = fmaf(e[2 * u + 2 + k], RL[k], s);
                    a1r[u] = s;
                }
                // a2[B0+m0+i], i=0,1: window a1r[2i .. 2i+7]
                float o[2];
                #pragma unroll
                for (int i = 0; i < 2; ++i) {
                    float s = a1r[2 * i] * RL[0];
                    #pragma unroll
                    for (int k = 1; k < 8; ++k)
                        s = fmaf(a1r[2 * i + k], RL[k], s);
                    o[i] = s;
                }
                *reinterpret_cast<float2*>(&sa2[m0]) = make_float2(o[0], o[1]);
            }
        }
        bar_lgkm();
    } else {
        // ==== edge: R13-verified staged pyramid with per-level reflection ====
        const int t0  = (tile == 0) ? 44 : 4;
        const int thi = (tile == 0) ? 1116 : 1068;
        const int Nv  = (thi - t0) >> 2;
        for (int v = tid; v < Nv; v += kThreads) {
            const float4 val = *reinterpret_cast<const float4*>(xr + XB + t0 + 4 * v);
            sx[t0 + 4 * v]     = val.x; sx[t0 + 4 * v + 1] = val.y;
            sx[t0 + 4 * v + 2] = val.z; sx[t0 + 4 * v + 3] = val.w;
        }
        for (int t = 2 + tid; t < 1116; t += kThreads)
            if (t < t0 || t >= thi)
                sx[t] = xr[reflect(XB + t, kL0)];
        bar_full();

        for (int m = tid; m < SA1; m += kThreads) {
            const int g  = A0 + m;
            const int mh = (g >= 0 && g < kN1) ? m : (reflect(g, kN1) - A0);
            sa1[m] = tap8f2(&sx[2 * mh + 2]);
        }
        bar_lgkm();

        for (int m = tid; m < SA2; m += kThreads) {
            const int g = B0 + m;
            const int j = (g >= 0 && g < kN2) ? m : (reflect(g, kN2) - B0);
            sa2[m] = tap8f2(&sa1[2 * j]);
        }
        bar_lgkm();
    }

    // ---- final: low[8*tid+r] = sum_j W2[r][j]*sa2[2*tid+j]; high = x - low ----
    {
        float b[20];
        #pragma unroll
        for (int j2 = 0; j2 < 10; ++j2) {
            const float2 v = *reinterpret_cast<const float2*>(&sa2[2 * tid + 2 * j2]);
            b[2 * j2]     = v.x;
            b[2 * j2 + 1] = v.y;
        }
        float lo[8];
        #pragma unroll
        for (int r = 0; r < 8; ++r) {
            float s = b[0] * W2.w[r][0];
            #pragma unroll
            for (int j = 1; j < 20; ++j) s = fmaf(b[j], W2.w[r][j], s);
            lo[r] = s;
        }
        float* __restrict__ lowp  = out + (size_t)row * kL0 + O + 8 * tid;
        float* __restrict__ highp = lowp + (size_t)rows * kL0;
        vfloat4 l0 = {lo[0], lo[1], lo[2], lo[3]};
        vfloat4 l1 = {lo[4], lo[5], lo[6], lo[7]};
        vfloat4 h0 = {xv0.x - lo[0], xv0.y - lo[1], xv0.z - lo[2], xv0.w - lo[3]};
        vfloat4 h1 = {xv1.x - lo[4], xv1.y - lo[5], xv1.z - lo[6], xv1.w - lo[7]};
        __builtin_nontemporal_store(l0, reinterpret_cast<vfloat4*>(lowp));
        __builtin_nontemporal_store(l1, reinterpret_cast<vfloat4*>(lowp) + 1);
        __builtin_nontemporal_store(h0, reinterpret_cast<vfloat4*>(highp));
        __builtin_nontemporal_store(h1, reinterpret_cast<vfloat4*>(highp) + 1);
    }
}

extern "C" void kernel_launch(void* const* d_in, const int* in_sizes, int n_in,
                              void* d_out, int out_size, void* d_ws, size_t ws_size,
                              hipStream_t stream) {
    (void)n_in; (void)d_ws; (void)ws_size; (void)out_size;
    const float* x = (const float*)d_in[0];
    float* out = (float*)d_out;
    const int rows = in_sizes[0] / kL0;                 // 2048
    const int blocks = rows * kTilesPerRow;             // 32768
    hipLaunchKernelGGL(wavelet_v16, dim3(blocks), dim3(kThreads), 0, stream,
                       x, out, rows);
}